// Round 6
// baseline (712.815 us; speedup 1.0000x reference)
//
#include <hip/hip_runtime.h>
#include <hip/hip_bf16.h>
#include <math.h>

#define HH 16
#define SS 2048
#define BBATCH 2
#define NROWS 4096   // B*S

typedef __attribute__((ext_vector_type(8))) __bf16 bf16x8;
typedef __attribute__((ext_vector_type(4))) float f32x4;
typedef const __attribute__((address_space(1))) unsigned int* gas1_t;
typedef __attribute__((address_space(3))) unsigned int* las3_t;

__device__ __forceinline__ unsigned short f2bf(float f) {
  unsigned u = __builtin_bit_cast(unsigned, f);
  u += 0x7fffu + ((u >> 16) & 1u);
  return (unsigned short)(u >> 16);
}

__device__ __forceinline__ void gload16(const void* g, void* l) {
  __builtin_amdgcn_global_load_lds((gas1_t)g, (las3_t)l, 16, 0, 0);
}
__device__ __forceinline__ f32x4 mfma16(bf16x8 a, bf16x8 b, f32x4 c) {
  return __builtin_amdgcn_mfma_f32_16x16x32_bf16(a, b, c, 0, 0, 0);
}

// ---------------- f32 -> bf16 copy (same layout) ----------------
__global__ __launch_bounds__(256) void k_convert(const float* __restrict__ in,
                                                 unsigned short* __restrict__ out, long n4) {
  long i = (long)blockIdx.x * blockDim.x + threadIdx.x;
  long stride = (long)gridDim.x * blockDim.x;
  for (; i < n4; i += stride) {
    float4 v = ((const float4*)in)[i];
    ushort4 o = { f2bf(v.x), f2bf(v.y), f2bf(v.z), f2bf(v.w) };
    ((ushort4*)out)[i] = o;
  }
}

// ---------------- W (K,N) f32 -> Wt (Npad,K) bf16 ----------------
__global__ __launch_bounds__(256) void k_transpose(const float* __restrict__ W,
                                                   unsigned short* __restrict__ Wt,
                                                   int K, int N, int Npad) {
  __shared__ float tile[32][33];
  int n0 = blockIdx.x * 32, k0 = blockIdx.y * 32;
  int tx = threadIdx.x & 31, ty = threadIdx.x >> 5;
  for (int i = ty; i < 32; i += 8) {
    int k = k0 + i, n = n0 + tx;
    tile[i][tx] = (k < K && n < N) ? W[(long)k * N + n] : 0.f;
  }
  __syncthreads();
  for (int i = ty; i < 32; i += 8) {
    int n = n0 + i, k = k0 + tx;
    if (n < Npad && k < K) Wt[(long)n * K + k] = f2bf(tile[tx][i]);
  }
}

// ---------------- GEMM: C(M,N) f32 = A(M,K)bf16 * Bt(Npad,K)bf16 + bias ----------------
__global__ __launch_bounds__(256) void k_gemm(const unsigned short* __restrict__ A,
                                              const unsigned short* __restrict__ Bt,
                                              const float* __restrict__ bias,
                                              float* __restrict__ C,
                                              int M, int N, int K) {
  __shared__ unsigned short lA[128 * 32];
  __shared__ unsigned short lB[128 * 32];
  int tid = threadIdx.x;
  int wave = tid >> 6, lane = tid & 63;
  int l15 = lane & 15, lhi = lane >> 4;
  int ntn = (N + 127) >> 7;
  int tm = blockIdx.x / ntn, tn = blockIdx.x % ntn;
  long row0 = (long)tm * 128, col0 = (long)tn * 128;
  int wr = wave >> 1, wc = wave & 1;

  const unsigned short* gA = A + (row0 + (tid >> 2)) * K + (tid & 3) * 8;
  const unsigned short* gB = Bt + (col0 + (tid >> 2)) * K + (tid & 3) * 8;
  unsigned short* lA0 = &lA[tid * 8];
  unsigned short* lB0 = &lB[tid * 8];

  f32x4 acc[4][4] = {};
  for (int k0 = 0; k0 < K; k0 += 32) {
    __syncthreads();
    gload16(gA + k0, lA0);
    gload16(gA + (long)64 * K + k0, lA0 + 2048);
    gload16(gB + k0, lB0);
    gload16(gB + (long)64 * K + k0, lB0 + 2048);
    asm volatile("s_waitcnt vmcnt(0)" ::: "memory");
    __syncthreads();
    bf16x8 af[4], bfr[4];
#pragma unroll
    for (int i = 0; i < 4; ++i) {
      af[i]  = *(const bf16x8*)&lA[(wr * 64 + i * 16 + l15) * 32 + lhi * 8];
      bfr[i] = *(const bf16x8*)&lB[(wc * 64 + i * 16 + l15) * 32 + lhi * 8];
    }
#pragma unroll
    for (int i = 0; i < 4; ++i)
#pragma unroll
      for (int j = 0; j < 4; ++j)
        acc[i][j] = mfma16(af[i], bfr[j], acc[i][j]);
  }
#pragma unroll
  for (int i = 0; i < 4; ++i)
#pragma unroll
    for (int j = 0; j < 4; ++j) {
      long r = row0 + wr * 64 + i * 16 + lhi * 4;
      long c = col0 + wc * 64 + j * 16 + l15;
      if (c < N) {
        float bv = bias[c];
#pragma unroll
        for (int rr = 0; rr < 4; ++rr)
          C[(r + rr) * N + c] = acc[i][j][rr] + bv;
      }
    }
}

// ---------------- RMSNorm: f32 (rows, ldx) -> bf16 (rows, L) ----------------
__global__ __launch_bounds__(256) void k_rmsnorm(const float* __restrict__ X,
                                                 const float* __restrict__ w,
                                                 unsigned short* __restrict__ Y,
                                                 int L, int ldx) {
  long row = blockIdx.x;
  const float* x = X + row * ldx;
  float ss = 0.f;
  int n4 = L >> 2;
  for (int i = threadIdx.x; i < n4; i += 256) {
    float4 v = ((const float4*)x)[i];
    ss += v.x * v.x + v.y * v.y + v.z * v.z + v.w * v.w;
  }
  for (int off = 32; off > 0; off >>= 1) ss += __shfl_xor(ss, off);
  __shared__ float sb[4];
  if ((threadIdx.x & 63) == 0) sb[threadIdx.x >> 6] = ss;
  __syncthreads();
  float scale = rsqrtf((sb[0] + sb[1] + sb[2] + sb[3]) / (float)L + 1e-6f);
  unsigned short* y = Y + row * L;
  for (int i = threadIdx.x; i < L; i += 256)
    y[i] = f2bf(x[i] * scale * w[i]);
}

// ---------------- q (NROWS,3072) f32 -> qf (B*H, S, 192) bf16, rope+scale ----------------
// scale includes log2(e) so attention softmax runs in exp2 domain
__global__ __launch_bounds__(256) void k_extract_q(const float* __restrict__ q,
                                                   unsigned short* __restrict__ qf) {
  int idx = blockIdx.x * 4 + (threadIdx.x >> 6);   // (b*S+s)*H + h
  int lane = threadIdx.x & 63;
  int h = idx & 15;
  int bs = idx >> 4;
  int s = bs & (SS - 1);
  const float* src = q + (long)idx * 192;
  long bh = (long)(bs >> 11) * HH + h;
  unsigned short* dst = qf + (bh * SS + s) * 192;
  const float scq = 0.07216878364870322f * 1.4426950408889634f;  // 192^-0.5 * log2(e)
  dst[lane]      = f2bf(src[lane] * scq);
  dst[lane + 64] = f2bf(src[lane + 64] * scq);
  if (lane < 32) {
    float inv = powf(10000.f, -(float)lane / 32.f);
    float ang = (float)s * inv;
    float sn, cs;
    sincosf(ang, &sn, &cs);
    float t1 = src[128 + lane], t2 = src[160 + lane];
    dst[128 + lane] = f2bf((t1 * cs - t2 * sn) * scq);
    dst[160 + lane] = f2bf((t2 * cs + t1 * sn) * scq);
  }
}

// ---------------- kvd rope cols -> kf[...,128:192] broadcast (linear) ----------------
__global__ __launch_bounds__(64) void k_extract_krope(const float* __restrict__ kvd,
                                                      unsigned short* __restrict__ kf) {
  int bs = blockIdx.x;
  int lane = threadIdx.x;
  int s = bs & (SS - 1), b = bs >> 11;
  const float* src = kvd + (long)bs * 576 + 512;
  int i = lane & 31;
  float inv = powf(10000.f, -(float)i / 32.f);
  float ang = (float)s * inv;
  float sn, cs;
  sincosf(ang, &sn, &cs);
  float t1 = src[i], t2 = src[32 + i];
  float v = (lane < 32) ? (t1 * cs - t2 * sn) : (t2 * cs + t1 * sn);
  unsigned short bv = f2bf(v);
#pragma unroll
  for (int h = 0; h < HH; ++h)
    kf[(((long)(b * HH + h)) * SS + s) * 192 + 128 + lane] = bv;
}

// ---------------- kvu (NROWS,4096) f32 -> kf nope (linear) + vt (B*H,128,S) ----------------
__global__ __launch_bounds__(256) void k_extract_kv(const float* __restrict__ kvu,
                                                    unsigned short* __restrict__ kf,
                                                    unsigned short* __restrict__ vt) {
  __shared__ unsigned short vtile[64][132];
  int blk = blockIdx.x;
  int st = blk & 31;
  int h = (blk >> 5) & 15;
  int b = blk >> 9;
  int s0 = st * 64;
  long bh = (long)b * HH + h;
#pragma unroll
  for (int it = 0; it < 16; ++it) {
    int v4 = it * 256 + threadIdx.x;
    int sl = v4 >> 6;
    int c = (v4 & 63) * 4;
    int s = s0 + sl;
    float4 val = *(const float4*)&kvu[(((long)(b * SS + s)) * HH + h) * 256 + c];
    ushort4 ov = { f2bf(val.x), f2bf(val.y), f2bf(val.z), f2bf(val.w) };
    if (c < 128) {
      *(ushort4*)&kf[(bh * SS + s) * 192 + c] = ov;
    } else {
      *(ushort4*)&vtile[sl][c - 128] = ov;
    }
  }
  __syncthreads();
#pragma unroll
  for (int it = 0; it < 32; ++it) {
    int e = it * 256 + threadIdx.x;
    int d = e >> 6, sl = e & 63;
    vt[(bh * 128 + d) * SS + s0 + sl] = vtile[sl][d];
  }
}

// ---------------- flash attention: barrier-free, direct-global K/V ----------------
// One block = one (bh, q-tile of 64 rows); 4 waves each own 16 q-rows and run
// fully independently (no __syncthreads / s_barrier in the kernel). K and V
// fragments are loaded straight from global (L2-resident per head; the 4
// waves issue identical K/V addresses so L1 coalesces them). Swapped QK^T
// keeps softmax lane-local (2 shfl per reduce). Dispatch order: heavy q-tiles
// first, same-bh blocks on the same XCD slot (idx%8) for L2 locality.
__global__ __launch_bounds__(256, 4) void k_attn(const unsigned short* __restrict__ qf,
                                                 const unsigned short* __restrict__ kf,
                                                 const unsigned short* __restrict__ vt,
                                                 unsigned short* __restrict__ o) {
  __shared__ unsigned short pbuf[4][16 * 72];   // per-wave P transpose buffer
  int tid = threadIdx.x;
  int wave = tid >> 6, lane = tid & 63;
  int l15 = lane & 15, lhi = lane >> 4;
  int idx = blockIdx.x;
  int bh = (idx & 7) * 4 + ((idx >> 3) & 3);    // same bh -> same idx%8 (XCD slot)
  int qt = 31 - (idx >> 5);                     // heavy tiles dispatched first
  int b = bh >> 4, h = bh & 15;
  int q0 = qt * 64;
  int nt = qt + 1;
  const unsigned short* kb = kf + (long)bh * SS * 192;
  const unsigned short* vb = vt + (long)bh * 128 * SS;

  // Q fragments (B-operand): lane holds Q[q0+wave*16+l15][k-chunk]
  const unsigned short* Qb = qf + ((long)bh * SS + q0 + wave * 16 + l15) * 192 + lhi * 8;
  bf16x8 qfr[6];
#pragma unroll
  for (int ks = 0; ks < 6; ++ks) qfr[ks] = *(const bf16x8*)(Qb + ks * 32);

  float m = -3e38f, ls = 0.f;
  f32x4 acc[8] = {};
  int qin = wave * 16 + l15;

  for (int t = 0; t < nt; ++t) {
    int kv0 = t * 64;
    const unsigned short* kt = kb + (long)(kv0 + l15) * 192 + lhi * 8;

    // QK^T (swapped): sc[nf] rows k=nf*16+lhi*4+j, col q=l15
    f32x4 sc[4] = {};
#pragma unroll
    for (int ks = 0; ks < 6; ++ks) {
      bf16x8 kfr[4];
#pragma unroll
      for (int nf = 0; nf < 4; ++nf)
        kfr[nf] = *(const bf16x8*)(kt + (long)nf * 16 * 192 + ks * 32);
#pragma unroll
      for (int nf = 0; nf < 4; ++nf)
        sc[nf] = mfma16(kfr[nf], qfr[ks], sc[nf]);
    }

    // online softmax, lane-local over k (tree reduce + 2 shfl)
    bool diag = (t == nt - 1);
    float mnf[4];
#pragma unroll
    for (int nf = 0; nf < 4; ++nf) {
      if (diag) {
#pragma unroll
        for (int j = 0; j < 4; ++j) {
          int kin = nf * 16 + lhi * 4 + j;
          if (kin > qin) sc[nf][j] = -3e38f;
        }
      }
      mnf[nf] = fmaxf(fmaxf(sc[nf][0], sc[nf][1]), fmaxf(sc[nf][2], sc[nf][3]));
    }
    float mx = fmaxf(fmaxf(mnf[0], mnf[1]), fmaxf(mnf[2], mnf[3]));
    mx = fmaxf(mx, __shfl_xor(mx, 16));
    mx = fmaxf(mx, __shfl_xor(mx, 32));
    if (!__all(mx <= m + 8.f)) {      // defer-rescale (exp2 domain, THR=8)
      float mn = fmaxf(m, mx);
      float alpha = exp2f(m - mn);
      m = mn;
      ls *= alpha;
#pragma unroll
      for (int nf = 0; nf < 8; ++nf)
#pragma unroll
        for (int j = 0; j < 4; ++j) acc[nf][j] *= alpha;
    }
    float pnf[4];
#pragma unroll
    for (int nf = 0; nf < 4; ++nf) {
      ushort4 pk;
      float e0 = exp2f(sc[nf][0] - m), e1 = exp2f(sc[nf][1] - m);
      float e2 = exp2f(sc[nf][2] - m), e3 = exp2f(sc[nf][3] - m);
      pnf[nf] = (e0 + e1) + (e2 + e3);
      pk.x = f2bf(e0); pk.y = f2bf(e1); pk.z = f2bf(e2); pk.w = f2bf(e3);
      *(ushort4*)&pbuf[wave][l15 * 72 + nf * 16 + lhi * 4] = pk;
    }
    float ps = (pnf[0] + pnf[1]) + (pnf[2] + pnf[3]);
    ps += __shfl_xor(ps, 16);
    ps += __shfl_xor(ps, 32);
    ls += ps;

    // PV: acc[nf] += V^T-frag x P^T-frag (V loaded inline from global)
#pragma unroll
    for (int kk = 0; kk < 2; ++kk) {
      bf16x8 pf = *(const bf16x8*)&pbuf[wave][l15 * 72 + kk * 32 + lhi * 8];
      const unsigned short* vk = vb + (long)l15 * SS + kv0 + kk * 32 + lhi * 8;
#pragma unroll
      for (int nf = 0; nf < 8; ++nf) {
        bf16x8 vf = *(const bf16x8*)(vk + (long)nf * 16 * SS);
        acc[nf] = mfma16(vf, pf, acc[nf]);
      }
    }
  }

  // epilogue: O^T frags, row q=l15, d = nf*16+lhi*4+j -> 8B stores
  float invl = 1.f / ls;
  long orow = (long)b * SS + q0 + wave * 16 + l15;
#pragma unroll
  for (int nf = 0; nf < 8; ++nf) {
    ushort4 ov = { f2bf(acc[nf][0] * invl), f2bf(acc[nf][1] * invl),
                   f2bf(acc[nf][2] * invl), f2bf(acc[nf][3] * invl) };
    *(ushort4*)&o[orow * 2048 + h * 128 + nf * 16 + lhi * 4] = ov;
  }
}

extern "C" void kernel_launch(void* const* d_in, const int* in_sizes, int n_in,
                              void* d_out, int out_size, void* d_ws, size_t ws_size,
                              hipStream_t stream) {
  const float* x    = (const float*)d_in[0];
  const float* wqd  = (const float*)d_in[1];
  const float* bqd  = (const float*)d_in[2];
  const float* qnw  = (const float*)d_in[3];
  const float* wqu  = (const float*)d_in[4];
  const float* bqu  = (const float*)d_in[5];
  const float* wkvd = (const float*)d_in[6];
  const float* bkvd = (const float*)d_in[7];
  const float* kvnw = (const float*)d_in[8];
  const float* wkvu = (const float*)d_in[9];
  const float* bkvu = (const float*)d_in[10];
  const float* wout = (const float*)d_in[11];
  const float* bout = (const float*)d_in[12];
  float* out = (float*)d_out;

  char* ws = (char*)d_ws;
  size_t off = 0;
  auto alloc = [&](size_t sz) {
    char* p = ws + off;
    off += (sz + 255) & ~(size_t)255;
    return p;
  };
  unsigned short* xb    = (unsigned short*)alloc((size_t)NROWS * 2048 * 2);
  unsigned short* wqdt  = (unsigned short*)alloc((size_t)1536 * 2048 * 2);
  unsigned short* wqut  = (unsigned short*)alloc((size_t)3072 * 1536 * 2);
  unsigned short* wkvdt = (unsigned short*)alloc((size_t)640 * 2048 * 2);
  unsigned short* wkvut = (unsigned short*)alloc((size_t)4096 * 512 * 2);
  unsigned short* woutt = (unsigned short*)alloc((size_t)2048 * 2048 * 2);
  unsigned short* qn    = (unsigned short*)alloc((size_t)NROWS * 1536 * 2);
  unsigned short* kvn   = (unsigned short*)alloc((size_t)NROWS * 512 * 2);
  unsigned short* qfb   = (unsigned short*)alloc((size_t)32 * SS * 192 * 2);
  unsigned short* kfb   = (unsigned short*)alloc((size_t)32 * SS * 192 * 2);
  unsigned short* vtb   = (unsigned short*)alloc((size_t)32 * 128 * SS * 2);
  unsigned short* ob    = (unsigned short*)alloc((size_t)NROWS * 2048 * 2);
  float* sA = (float*)alloc((size_t)NROWS * 1536 * 4);   // qd, then kvd
  float* sB = (float*)alloc((size_t)NROWS * 4096 * 4);   // q,  then kvu

  // conversions
  k_convert<<<2048, 256, 0, stream>>>(x, xb, (long)NROWS * 2048 / 4);
  k_transpose<<<dim3(48, 64), 256, 0, stream>>>(wqd, wqdt, 2048, 1536, 1536);
  k_transpose<<<dim3(96, 48), 256, 0, stream>>>(wqu, wqut, 1536, 3072, 3072);
  k_transpose<<<dim3(20, 64), 256, 0, stream>>>(wkvd, wkvdt, 2048, 576, 640);
  k_transpose<<<dim3(128, 16), 256, 0, stream>>>(wkvu, wkvut, 512, 4096, 4096);
  k_transpose<<<dim3(64, 64), 256, 0, stream>>>(wout, woutt, 2048, 2048, 2048);

  // q path
  k_gemm<<<32 * 12, 256, 0, stream>>>(xb, wqdt, bqd, sA, NROWS, 1536, 2048);
  k_rmsnorm<<<NROWS, 256, 0, stream>>>(sA, qnw, qn, 1536, 1536);
  k_gemm<<<32 * 24, 256, 0, stream>>>(qn, wqut, bqu, sB, NROWS, 3072, 1536);
  k_extract_q<<<NROWS * HH / 4, 256, 0, stream>>>(sB, qfb);

  // kv path
  k_gemm<<<32 * 5, 256, 0, stream>>>(xb, wkvdt, bkvd, sA, NROWS, 576, 2048);
  k_rmsnorm<<<NROWS, 256, 0, stream>>>(sA, kvnw, kvn, 512, 576);
  k_extract_krope<<<NROWS, 64, 0, stream>>>(sA, kfb);
  k_gemm<<<32 * 32, 256, 0, stream>>>(kvn, wkvut, bkvu, sB, NROWS, 4096, 512);
  k_extract_kv<<<1024, 256, 0, stream>>>(sB, kfb, vtb);

  // attention: 1024 blocks (32 bh x 32 q-tiles), barrier-free, 4 blocks/CU
  k_attn<<<1024, 256, 0, stream>>>(qfb, kfb, vtb, ob);

  // output projection
  k_gemm<<<32 * 16, 256, 0, stream>>>(ob, woutt, bout, out, NROWS, 2048, 2048);
}

// Round 7
// 524.833 us; speedup vs baseline: 1.3582x; 1.3582x over previous
//
#include <hip/hip_runtime.h>
#include <hip/hip_bf16.h>
#include <math.h>

#define HH 16
#define SS 2048
#define BBATCH 2
#define NROWS 4096   // B*S

typedef __attribute__((ext_vector_type(8))) __bf16 bf16x8;
typedef __attribute__((ext_vector_type(4))) float f32x4;
typedef const __attribute__((address_space(1))) unsigned int* gas1_t;
typedef __attribute__((address_space(3))) unsigned int* las3_t;

__device__ __forceinline__ unsigned short f2bf(float f) {
  unsigned u = __builtin_bit_cast(unsigned, f);
  u += 0x7fffu + ((u >> 16) & 1u);
  return (unsigned short)(u >> 16);
}

__device__ __forceinline__ void gload16(const void* g, void* l) {
  __builtin_amdgcn_global_load_lds((gas1_t)g, (las3_t)l, 16, 0, 0);
}
__device__ __forceinline__ f32x4 mfma16(bf16x8 a, bf16x8 b, f32x4 c) {
  return __builtin_amdgcn_mfma_f32_16x16x32_bf16(a, b, c, 0, 0, 0);
}

// ---------------- f32 -> bf16 copy (same layout) ----------------
__global__ __launch_bounds__(256) void k_convert(const float* __restrict__ in,
                                                 unsigned short* __restrict__ out, long n4) {
  long i = (long)blockIdx.x * blockDim.x + threadIdx.x;
  long stride = (long)gridDim.x * blockDim.x;
  for (; i < n4; i += stride) {
    float4 v = ((const float4*)in)[i];
    ushort4 o = { f2bf(v.x), f2bf(v.y), f2bf(v.z), f2bf(v.w) };
    ((ushort4*)out)[i] = o;
  }
}

// ---------------- W (K,N) f32 -> Wt (Npad,K) bf16 ----------------
__global__ __launch_bounds__(256) void k_transpose(const float* __restrict__ W,
                                                   unsigned short* __restrict__ Wt,
                                                   int K, int N, int Npad) {
  __shared__ float tile[32][33];
  int n0 = blockIdx.x * 32, k0 = blockIdx.y * 32;
  int tx = threadIdx.x & 31, ty = threadIdx.x >> 5;
  for (int i = ty; i < 32; i += 8) {
    int k = k0 + i, n = n0 + tx;
    tile[i][tx] = (k < K && n < N) ? W[(long)k * N + n] : 0.f;
  }
  __syncthreads();
  for (int i = ty; i < 32; i += 8) {
    int n = n0 + i, k = k0 + tx;
    if (n < Npad && k < K) Wt[(long)n * K + k] = f2bf(tile[tx][i]);
  }
}

// ---------------- GEMM: C(M,N) f32 = A(M,K)bf16 * Bt(Npad,K)bf16 + bias ----------------
__global__ __launch_bounds__(256) void k_gemm(const unsigned short* __restrict__ A,
                                              const unsigned short* __restrict__ Bt,
                                              const float* __restrict__ bias,
                                              float* __restrict__ C,
                                              int M, int N, int K) {
  __shared__ unsigned short lA[128 * 32];
  __shared__ unsigned short lB[128 * 32];
  int tid = threadIdx.x;
  int wave = tid >> 6, lane = tid & 63;
  int l15 = lane & 15, lhi = lane >> 4;
  int ntn = (N + 127) >> 7;
  int tm = blockIdx.x / ntn, tn = blockIdx.x % ntn;
  long row0 = (long)tm * 128, col0 = (long)tn * 128;
  int wr = wave >> 1, wc = wave & 1;

  const unsigned short* gA = A + (row0 + (tid >> 2)) * K + (tid & 3) * 8;
  const unsigned short* gB = Bt + (col0 + (tid >> 2)) * K + (tid & 3) * 8;
  unsigned short* lA0 = &lA[tid * 8];
  unsigned short* lB0 = &lB[tid * 8];

  f32x4 acc[4][4] = {};
  for (int k0 = 0; k0 < K; k0 += 32) {
    __syncthreads();
    gload16(gA + k0, lA0);
    gload16(gA + (long)64 * K + k0, lA0 + 2048);
    gload16(gB + k0, lB0);
    gload16(gB + (long)64 * K + k0, lB0 + 2048);
    asm volatile("s_waitcnt vmcnt(0)" ::: "memory");
    __syncthreads();
    bf16x8 af[4], bfr[4];
#pragma unroll
    for (int i = 0; i < 4; ++i) {
      af[i]  = *(const bf16x8*)&lA[(wr * 64 + i * 16 + l15) * 32 + lhi * 8];
      bfr[i] = *(const bf16x8*)&lB[(wc * 64 + i * 16 + l15) * 32 + lhi * 8];
    }
#pragma unroll
    for (int i = 0; i < 4; ++i)
#pragma unroll
      for (int j = 0; j < 4; ++j)
        acc[i][j] = mfma16(af[i], bfr[j], acc[i][j]);
  }
#pragma unroll
  for (int i = 0; i < 4; ++i)
#pragma unroll
    for (int j = 0; j < 4; ++j) {
      long r = row0 + wr * 64 + i * 16 + lhi * 4;
      long c = col0 + wc * 64 + j * 16 + l15;
      if (c < N) {
        float bv = bias[c];
#pragma unroll
        for (int rr = 0; rr < 4; ++rr)
          C[(r + rr) * N + c] = acc[i][j][rr] + bv;
      }
    }
}

// ---------------- RMSNorm: f32 (rows, ldx) -> bf16 (rows, L) ----------------
__global__ __launch_bounds__(256) void k_rmsnorm(const float* __restrict__ X,
                                                 const float* __restrict__ w,
                                                 unsigned short* __restrict__ Y,
                                                 int L, int ldx) {
  long row = blockIdx.x;
  const float* x = X + row * ldx;
  float ss = 0.f;
  int n4 = L >> 2;
  for (int i = threadIdx.x; i < n4; i += 256) {
    float4 v = ((const float4*)x)[i];
    ss += v.x * v.x + v.y * v.y + v.z * v.z + v.w * v.w;
  }
  for (int off = 32; off > 0; off >>= 1) ss += __shfl_xor(ss, off);
  __shared__ float sb[4];
  if ((threadIdx.x & 63) == 0) sb[threadIdx.x >> 6] = ss;
  __syncthreads();
  float scale = rsqrtf((sb[0] + sb[1] + sb[2] + sb[3]) / (float)L + 1e-6f);
  unsigned short* y = Y + row * L;
  for (int i = threadIdx.x; i < L; i += 256)
    y[i] = f2bf(x[i] * scale * w[i]);
}

// ---------------- q (NROWS,3072) f32 -> qf (B*H, S, 192) bf16, rope+scale ----------------
// scale includes log2(e) so attention softmax runs in exp2 domain
__global__ __launch_bounds__(256) void k_extract_q(const float* __restrict__ q,
                                                   unsigned short* __restrict__ qf) {
  int idx = blockIdx.x * 4 + (threadIdx.x >> 6);   // (b*S+s)*H + h
  int lane = threadIdx.x & 63;
  int h = idx & 15;
  int bs = idx >> 4;
  int s = bs & (SS - 1);
  const float* src = q + (long)idx * 192;
  long bh = (long)(bs >> 11) * HH + h;
  unsigned short* dst = qf + (bh * SS + s) * 192;
  const float scq = 0.07216878364870322f * 1.4426950408889634f;  // 192^-0.5 * log2(e)
  dst[lane]      = f2bf(src[lane] * scq);
  dst[lane + 64] = f2bf(src[lane + 64] * scq);
  if (lane < 32) {
    float inv = powf(10000.f, -(float)lane / 32.f);
    float ang = (float)s * inv;
    float sn, cs;
    sincosf(ang, &sn, &cs);
    float t1 = src[128 + lane], t2 = src[160 + lane];
    dst[128 + lane] = f2bf((t1 * cs - t2 * sn) * scq);
    dst[160 + lane] = f2bf((t2 * cs + t1 * sn) * scq);
  }
}

// K fragment-tiled layout:
//   kf3[bh][s>>4][ks(6)][s&15][d&31]  (1KB per [16][32] tile)
// addr(bh,s,d) = (((bh*128 + (s>>4))*6 + (d>>5))*512) + (s&15)*32 + (d&31)
// V fragment-tiled layout:
//   vt3[bh][s>>5][d(128)][s&31]      (8KB per 32-s slab; [16][32] tile per nf)
// addr(bh,s,d) = ((bh*64 + (s>>5))*4096) + d*32 + (s&31)

// ---------------- kvd rope cols -> kf3 d=128..191, broadcast over heads ----------------
__global__ __launch_bounds__(64) void k_extract_krope(const float* __restrict__ kvd,
                                                      unsigned short* __restrict__ kf3) {
  int bs = blockIdx.x;
  int lane = threadIdx.x;
  int s = bs & (SS - 1), b = bs >> 11;
  const float* src = kvd + (long)bs * 576 + 512;
  int i = lane & 31;
  float inv = powf(10000.f, -(float)i / 32.f);
  float ang = (float)s * inv;
  float sn, cs;
  sincosf(ang, &sn, &cs);
  float t1 = src[i], t2 = src[32 + i];
  float v = (lane < 32) ? (t1 * cs - t2 * sn) : (t2 * cs + t1 * sn);
  unsigned short bv = f2bf(v);
  int d = 128 + lane;
  long inner = (long)(d >> 5) * 512 + (s & 15) * 32 + (d & 31);
#pragma unroll
  for (int h = 0; h < HH; ++h) {
    long blk = ((long)(b * HH + h) * 128 + (s >> 4)) * 6;
    kf3[blk * 512 + inner] = bv;
  }
}

// ---------------- kvu (NROWS,4096) f32 -> kf3 nope + vt3 ----------------
__global__ __launch_bounds__(256) void k_extract_kv(const float* __restrict__ kvu,
                                                    unsigned short* __restrict__ kf3,
                                                    unsigned short* __restrict__ vt3) {
  __shared__ unsigned short vtile[64][132];
  int blk = blockIdx.x;
  int st = blk & 31;
  int h = (blk >> 5) & 15;
  int b = blk >> 9;
  int s0 = st * 64;
  long bh = (long)b * HH + h;
#pragma unroll
  for (int it = 0; it < 16; ++it) {
    int v4 = it * 256 + threadIdx.x;
    int sl = v4 >> 6;
    int c = (v4 & 63) * 4;
    int s = s0 + sl;
    float4 val = *(const float4*)&kvu[(((long)(b * SS + s)) * HH + h) * 256 + c];
    ushort4 ov = { f2bf(val.x), f2bf(val.y), f2bf(val.z), f2bf(val.w) };
    if (c < 128) {
      long addr = ((bh * 128 + (s >> 4)) * 6 + (c >> 5)) * 512 + (s & 15) * 32 + (c & 31);
      *(ushort4*)&kf3[addr] = ov;
    } else {
      *(ushort4*)&vtile[sl][c - 128] = ov;
    }
  }
  __syncthreads();
#pragma unroll
  for (int it = 0; it < 32; ++it) {
    int e = it * 256 + threadIdx.x;
    int d = e >> 6, sl = e & 63;
    vt3[(bh * 64 + st * 2 + (sl >> 5)) * 4096 + d * 32 + (sl & 31)] = vtile[sl][d];
  }
}

// ---------------- flash attention: barrier-free, fragment-tiled direct-global K/V ----------------
// One block = one (bh, q-tile of 64 rows); 4 waves own 16 q-rows each, fully
// independent (no block-level sync). Every K/V fragment load is one contiguous
// 1KB wave-load (lane addr = l15*64B + lhi*16B) from the L2-resident tiled
// buffers — 40 L2-coalesced loads per wave-iteration instead of 2560
// divergent transactions. Swapped QK^T keeps softmax lane-local.
__global__ __launch_bounds__(256, 3) void k_attn(const unsigned short* __restrict__ qf,
                                                 const unsigned short* __restrict__ kf3,
                                                 const unsigned short* __restrict__ vt3,
                                                 unsigned short* __restrict__ o) {
  __shared__ unsigned short pbuf[4][16 * 72];   // per-wave P transpose buffer
  int tid = threadIdx.x;
  int wave = tid >> 6, lane = tid & 63;
  int l15 = lane & 15, lhi = lane >> 4;
  int idx = blockIdx.x;
  int bh = (idx & 7) * 4 + ((idx >> 3) & 3);    // same bh -> same idx%8 (XCD slot)
  int qt = 31 - (idx >> 5);                     // heavy tiles dispatched first
  int b = bh >> 4, h = bh & 15;
  int q0 = qt * 64;
  int nt = qt + 1;
  const unsigned short* kfrag0 = kf3 + (long)bh * 128 * 3072 + l15 * 32 + lhi * 8;
  const unsigned short* vfrag0 = vt3 + (long)bh * 64 * 4096 + l15 * 32 + lhi * 8;

  // Q fragments (B-operand): lane holds Q[q0+wave*16+l15][k-chunk]
  const unsigned short* Qb = qf + ((long)bh * SS + q0 + wave * 16 + l15) * 192 + lhi * 8;
  bf16x8 qfr[6];
#pragma unroll
  for (int ks = 0; ks < 6; ++ks) qfr[ks] = *(const bf16x8*)(Qb + ks * 32);

  float m = -3e38f, ls = 0.f;
  f32x4 acc[8] = {};
  int qin = wave * 16 + l15;

  for (int t = 0; t < nt; ++t) {
    const unsigned short* kt = kfrag0 + (long)t * 4 * 3072;   // 4 s-subtiles x 6 ks x 512
    const unsigned short* vtb = vfrag0 + (long)t * 2 * 4096;  // 2 kk-slabs x 8 nf x 512

    // V slice 0 prefetch (consumed in PV kk=0) — issued before QK^T
    bf16x8 v0[8];
#pragma unroll
    for (int nf = 0; nf < 8; ++nf)
      v0[nf] = *(const bf16x8*)(vtb + nf * 512);

    // QK^T (swapped): sc[nf] rows k=nf*16+lhi*4+j, col q=l15
    f32x4 sc[4] = {};
#pragma unroll
    for (int ks = 0; ks < 6; ++ks) {
      bf16x8 kfr[4];
#pragma unroll
      for (int nf = 0; nf < 4; ++nf)
        kfr[nf] = *(const bf16x8*)(kt + (nf * 6 + ks) * 512);
#pragma unroll
      for (int nf = 0; nf < 4; ++nf)
        sc[nf] = mfma16(kfr[nf], qfr[ks], sc[nf]);
    }

    // online softmax, lane-local over k (tree reduce + 2 shfl)
    bool diag = (t == nt - 1);
    float mnf[4];
#pragma unroll
    for (int nf = 0; nf < 4; ++nf) {
      if (diag) {
#pragma unroll
        for (int j = 0; j < 4; ++j) {
          int kin = nf * 16 + lhi * 4 + j;
          if (kin > qin) sc[nf][j] = -3e38f;
        }
      }
      mnf[nf] = fmaxf(fmaxf(sc[nf][0], sc[nf][1]), fmaxf(sc[nf][2], sc[nf][3]));
    }
    float mx = fmaxf(fmaxf(mnf[0], mnf[1]), fmaxf(mnf[2], mnf[3]));
    mx = fmaxf(mx, __shfl_xor(mx, 16));
    mx = fmaxf(mx, __shfl_xor(mx, 32));
    if (!__all(mx <= m + 8.f)) {      // defer-rescale (exp2 domain, THR=8)
      float mn = fmaxf(m, mx);
      float alpha = exp2f(m - mn);
      m = mn;
      ls *= alpha;
#pragma unroll
      for (int nf = 0; nf < 8; ++nf)
#pragma unroll
        for (int j = 0; j < 4; ++j) acc[nf][j] *= alpha;
    }
    float pnf[4];
#pragma unroll
    for (int nf = 0; nf < 4; ++nf) {
      ushort4 pk;
      float e0 = exp2f(sc[nf][0] - m), e1 = exp2f(sc[nf][1] - m);
      float e2 = exp2f(sc[nf][2] - m), e3 = exp2f(sc[nf][3] - m);
      pnf[nf] = (e0 + e1) + (e2 + e3);
      pk.x = f2bf(e0); pk.y = f2bf(e1); pk.z = f2bf(e2); pk.w = f2bf(e3);
      *(ushort4*)&pbuf[wave][l15 * 72 + nf * 16 + lhi * 4] = pk;
    }
    float ps = (pnf[0] + pnf[1]) + (pnf[2] + pnf[3]);
    ps += __shfl_xor(ps, 16);
    ps += __shfl_xor(ps, 32);
    ls += ps;

    // V slice 1 prefetch (hides under PV kk=0)
    bf16x8 v1[8];
#pragma unroll
    for (int nf = 0; nf < 8; ++nf)
      v1[nf] = *(const bf16x8*)(vtb + 4096 + nf * 512);

    // PV: acc[nf] += V^T-frag x P^T-frag
    {
      bf16x8 pf = *(const bf16x8*)&pbuf[wave][l15 * 72 + lhi * 8];
#pragma unroll
      for (int nf = 0; nf < 8; ++nf)
        acc[nf] = mfma16(v0[nf], pf, acc[nf]);
    }
    {
      bf16x8 pf = *(const bf16x8*)&pbuf[wave][l15 * 72 + 32 + lhi * 8];
#pragma unroll
      for (int nf = 0; nf < 8; ++nf)
        acc[nf] = mfma16(v1[nf], pf, acc[nf]);
    }
  }

  // epilogue: O^T frags, row q=l15, d = nf*16+lhi*4+j -> 8B stores
  float invl = 1.f / ls;
  long orow = (long)b * SS + q0 + wave * 16 + l15;
#pragma unroll
  for (int nf = 0; nf < 8; ++nf) {
    ushort4 ov = { f2bf(acc[nf][0] * invl), f2bf(acc[nf][1] * invl),
                   f2bf(acc[nf][2] * invl), f2bf(acc[nf][3] * invl) };
    *(ushort4*)&o[orow * 2048 + h * 128 + nf * 16 + lhi * 4] = ov;
  }
}

extern "C" void kernel_launch(void* const* d_in, const int* in_sizes, int n_in,
                              void* d_out, int out_size, void* d_ws, size_t ws_size,
                              hipStream_t stream) {
  const float* x    = (const float*)d_in[0];
  const float* wqd  = (const float*)d_in[1];
  const float* bqd  = (const float*)d_in[2];
  const float* qnw  = (const float*)d_in[3];
  const float* wqu  = (const float*)d_in[4];
  const float* bqu  = (const float*)d_in[5];
  const float* wkvd = (const float*)d_in[6];
  const float* bkvd = (const float*)d_in[7];
  const float* kvnw = (const float*)d_in[8];
  const float* wkvu = (const float*)d_in[9];
  const float* bkvu = (const float*)d_in[10];
  const float* wout = (const float*)d_in[11];
  const float* bout = (const float*)d_in[12];
  float* out = (float*)d_out;

  char* ws = (char*)d_ws;
  size_t off = 0;
  auto alloc = [&](size_t sz) {
    char* p = ws + off;
    off += (sz + 255) & ~(size_t)255;
    return p;
  };
  unsigned short* xb    = (unsigned short*)alloc((size_t)NROWS * 2048 * 2);
  unsigned short* wqdt  = (unsigned short*)alloc((size_t)1536 * 2048 * 2);
  unsigned short* wqut  = (unsigned short*)alloc((size_t)3072 * 1536 * 2);
  unsigned short* wkvdt = (unsigned short*)alloc((size_t)640 * 2048 * 2);
  unsigned short* wkvut = (unsigned short*)alloc((size_t)4096 * 512 * 2);
  unsigned short* woutt = (unsigned short*)alloc((size_t)2048 * 2048 * 2);
  unsigned short* qn    = (unsigned short*)alloc((size_t)NROWS * 1536 * 2);
  unsigned short* kvn   = (unsigned short*)alloc((size_t)NROWS * 512 * 2);
  unsigned short* qfb   = (unsigned short*)alloc((size_t)32 * SS * 192 * 2);
  unsigned short* kfb   = (unsigned short*)alloc((size_t)32 * SS * 192 * 2);   // kf3 tiled
  unsigned short* vtb   = (unsigned short*)alloc((size_t)32 * 128 * SS * 2);   // vt3 tiled
  unsigned short* ob    = (unsigned short*)alloc((size_t)NROWS * 2048 * 2);
  float* sA = (float*)alloc((size_t)NROWS * 1536 * 4);   // qd, then kvd
  float* sB = (float*)alloc((size_t)NROWS * 4096 * 4);   // q,  then kvu

  // conversions
  k_convert<<<2048, 256, 0, stream>>>(x, xb, (long)NROWS * 2048 / 4);
  k_transpose<<<dim3(48, 64), 256, 0, stream>>>(wqd, wqdt, 2048, 1536, 1536);
  k_transpose<<<dim3(96, 48), 256, 0, stream>>>(wqu, wqut, 1536, 3072, 3072);
  k_transpose<<<dim3(20, 64), 256, 0, stream>>>(wkvd, wkvdt, 2048, 576, 640);
  k_transpose<<<dim3(128, 16), 256, 0, stream>>>(wkvu, wkvut, 512, 4096, 4096);
  k_transpose<<<dim3(64, 64), 256, 0, stream>>>(wout, woutt, 2048, 2048, 2048);

  // q path
  k_gemm<<<32 * 12, 256, 0, stream>>>(xb, wqdt, bqd, sA, NROWS, 1536, 2048);
  k_rmsnorm<<<NROWS, 256, 0, stream>>>(sA, qnw, qn, 1536, 1536);
  k_gemm<<<32 * 24, 256, 0, stream>>>(qn, wqut, bqu, sB, NROWS, 3072, 1536);
  k_extract_q<<<NROWS * HH / 4, 256, 0, stream>>>(sB, qfb);

  // kv path
  k_gemm<<<32 * 5, 256, 0, stream>>>(xb, wkvdt, bkvd, sA, NROWS, 576, 2048);
  k_rmsnorm<<<NROWS, 256, 0, stream>>>(sA, kvnw, kvn, 512, 576);
  k_extract_krope<<<NROWS, 64, 0, stream>>>(sA, kfb);
  k_gemm<<<32 * 32, 256, 0, stream>>>(kvn, wkvut, bkvu, sB, NROWS, 4096, 512);
  k_extract_kv<<<1024, 256, 0, stream>>>(sB, kfb, vtb);

  // attention: 1024 blocks (32 bh x 32 q-tiles), barrier-free, fragment-tiled K/V
  k_attn<<<1024, 256, 0, stream>>>(qfb, kfb, vtb, ob);

  // output projection
  k_gemm<<<32 * 16, 256, 0, stream>>>(ob, woutt, bout, out, NROWS, 2048, 2048);
}

// Round 8
// 472.557 us; speedup vs baseline: 1.5084x; 1.1106x over previous
//
#include <hip/hip_runtime.h>
#include <hip/hip_bf16.h>
#include <math.h>

#define HH 16
#define SS 2048
#define BBATCH 2
#define NROWS 4096   // B*S

typedef __attribute__((ext_vector_type(8))) __bf16 bf16x8;
typedef __attribute__((ext_vector_type(4))) float f32x4;
typedef const __attribute__((address_space(1))) unsigned int* gas1_t;
typedef __attribute__((address_space(3))) unsigned int* las3_t;

__device__ __forceinline__ unsigned short f2bf(float f) {
  unsigned u = __builtin_bit_cast(unsigned, f);
  u += 0x7fffu + ((u >> 16) & 1u);
  return (unsigned short)(u >> 16);
}

__device__ __forceinline__ void gload16(const void* g, void* l) {
  __builtin_amdgcn_global_load_lds((gas1_t)g, (las3_t)l, 16, 0, 0);
}
__device__ __forceinline__ f32x4 mfma16(bf16x8 a, bf16x8 b, f32x4 c) {
  return __builtin_amdgcn_mfma_f32_16x16x32_bf16(a, b, c, 0, 0, 0);
}

// ---------------- f32 -> bf16 copy (same layout) ----------------
__global__ __launch_bounds__(256) void k_convert(const float* __restrict__ in,
                                                 unsigned short* __restrict__ out, long n4) {
  long i = (long)blockIdx.x * blockDim.x + threadIdx.x;
  long stride = (long)gridDim.x * blockDim.x;
  for (; i < n4; i += stride) {
    float4 v = ((const float4*)in)[i];
    ushort4 o = { f2bf(v.x), f2bf(v.y), f2bf(v.z), f2bf(v.w) };
    ((ushort4*)out)[i] = o;
  }
}

// ---------------- W (K,N) f32 -> Wt (Npad,K) bf16 ----------------
__global__ __launch_bounds__(256) void k_transpose(const float* __restrict__ W,
                                                   unsigned short* __restrict__ Wt,
                                                   int K, int N, int Npad) {
  __shared__ float tile[32][33];
  int n0 = blockIdx.x * 32, k0 = blockIdx.y * 32;
  int tx = threadIdx.x & 31, ty = threadIdx.x >> 5;
  for (int i = ty; i < 32; i += 8) {
    int k = k0 + i, n = n0 + tx;
    tile[i][tx] = (k < K && n < N) ? W[(long)k * N + n] : 0.f;
  }
  __syncthreads();
  for (int i = ty; i < 32; i += 8) {
    int n = n0 + i, k = k0 + tx;
    if (n < Npad && k < K) Wt[(long)n * K + k] = f2bf(tile[tx][i]);
  }
}

// ---------------- GEMM: C(M,N) f32 = A(M,K)bf16 * Bt(Npad,K)bf16 + bias ----------------
__global__ __launch_bounds__(256) void k_gemm(const unsigned short* __restrict__ A,
                                              const unsigned short* __restrict__ Bt,
                                              const float* __restrict__ bias,
                                              float* __restrict__ C,
                                              int M, int N, int K) {
  __shared__ unsigned short lA[128 * 32];
  __shared__ unsigned short lB[128 * 32];
  int tid = threadIdx.x;
  int wave = tid >> 6, lane = tid & 63;
  int l15 = lane & 15, lhi = lane >> 4;
  int ntn = (N + 127) >> 7;
  int tm = blockIdx.x / ntn, tn = blockIdx.x % ntn;
  long row0 = (long)tm * 128, col0 = (long)tn * 128;
  int wr = wave >> 1, wc = wave & 1;

  const unsigned short* gA = A + (row0 + (tid >> 2)) * K + (tid & 3) * 8;
  const unsigned short* gB = Bt + (col0 + (tid >> 2)) * K + (tid & 3) * 8;
  unsigned short* lA0 = &lA[tid * 8];
  unsigned short* lB0 = &lB[tid * 8];

  f32x4 acc[4][4] = {};
  for (int k0 = 0; k0 < K; k0 += 32) {
    __syncthreads();
    gload16(gA + k0, lA0);
    gload16(gA + (long)64 * K + k0, lA0 + 2048);
    gload16(gB + k0, lB0);
    gload16(gB + (long)64 * K + k0, lB0 + 2048);
    asm volatile("s_waitcnt vmcnt(0)" ::: "memory");
    __syncthreads();
    bf16x8 af[4], bfr[4];
#pragma unroll
    for (int i = 0; i < 4; ++i) {
      af[i]  = *(const bf16x8*)&lA[(wr * 64 + i * 16 + l15) * 32 + lhi * 8];
      bfr[i] = *(const bf16x8*)&lB[(wc * 64 + i * 16 + l15) * 32 + lhi * 8];
    }
#pragma unroll
    for (int i = 0; i < 4; ++i)
#pragma unroll
      for (int j = 0; j < 4; ++j)
        acc[i][j] = mfma16(af[i], bfr[j], acc[i][j]);
  }
#pragma unroll
  for (int i = 0; i < 4; ++i)
#pragma unroll
    for (int j = 0; j < 4; ++j) {
      long r = row0 + wr * 64 + i * 16 + lhi * 4;
      long c = col0 + wc * 64 + j * 16 + l15;
      if (c < N) {
        float bv = bias[c];
#pragma unroll
        for (int rr = 0; rr < 4; ++rr)
          C[(r + rr) * N + c] = acc[i][j][rr] + bv;
      }
    }
}

// ---------------- RMSNorm: f32 (rows, ldx) -> bf16 (rows, L) ----------------
__global__ __launch_bounds__(256) void k_rmsnorm(const float* __restrict__ X,
                                                 const float* __restrict__ w,
                                                 unsigned short* __restrict__ Y,
                                                 int L, int ldx) {
  long row = blockIdx.x;
  const float* x = X + row * ldx;
  float ss = 0.f;
  int n4 = L >> 2;
  for (int i = threadIdx.x; i < n4; i += 256) {
    float4 v = ((const float4*)x)[i];
    ss += v.x * v.x + v.y * v.y + v.z * v.z + v.w * v.w;
  }
  for (int off = 32; off > 0; off >>= 1) ss += __shfl_xor(ss, off);
  __shared__ float sb[4];
  if ((threadIdx.x & 63) == 0) sb[threadIdx.x >> 6] = ss;
  __syncthreads();
  float scale = rsqrtf((sb[0] + sb[1] + sb[2] + sb[3]) / (float)L + 1e-6f);
  unsigned short* y = Y + row * L;
  for (int i = threadIdx.x; i < L; i += 256)
    y[i] = f2bf(x[i] * scale * w[i]);
}

// ---------------- q (NROWS,3072) f32 -> qf (B*H, S, 192) bf16, rope+scale ----------------
// scale includes log2(e) so attention softmax runs in exp2 domain
__global__ __launch_bounds__(256) void k_extract_q(const float* __restrict__ q,
                                                   unsigned short* __restrict__ qf) {
  int idx = blockIdx.x * 4 + (threadIdx.x >> 6);   // (b*S+s)*H + h
  int lane = threadIdx.x & 63;
  int h = idx & 15;
  int bs = idx >> 4;
  int s = bs & (SS - 1);
  const float* src = q + (long)idx * 192;
  long bh = (long)(bs >> 11) * HH + h;
  unsigned short* dst = qf + (bh * SS + s) * 192;
  const float scq = 0.07216878364870322f * 1.4426950408889634f;  // 192^-0.5 * log2(e)
  dst[lane]      = f2bf(src[lane] * scq);
  dst[lane + 64] = f2bf(src[lane + 64] * scq);
  if (lane < 32) {
    float inv = powf(10000.f, -(float)lane / 32.f);
    float ang = (float)s * inv;
    float sn, cs;
    sincosf(ang, &sn, &cs);
    float t1 = src[128 + lane], t2 = src[160 + lane];
    dst[128 + lane] = f2bf((t1 * cs - t2 * sn) * scq);
    dst[160 + lane] = f2bf((t2 * cs + t1 * sn) * scq);
  }
}

// K fragment-tiled + bank-swizzled layout:
//   kf3[bh][s>>4][ks(6)][s&15][ (d&31) ^ ((s&3)<<3) ]   (1KB per [16][32] tile)
// V fragment-tiled layout (unswizzled — global loads don't bank-conflict):
//   vt3[bh][s>>5][d(128)][s&31]

// ---------------- kvd rope cols -> kf3 d=128..191, broadcast over heads ----------------
__global__ __launch_bounds__(64) void k_extract_krope(const float* __restrict__ kvd,
                                                      unsigned short* __restrict__ kf3) {
  int bs = blockIdx.x;
  int lane = threadIdx.x;
  int s = bs & (SS - 1), b = bs >> 11;
  const float* src = kvd + (long)bs * 576 + 512;
  int i = lane & 31;
  float inv = powf(10000.f, -(float)i / 32.f);
  float ang = (float)s * inv;
  float sn, cs;
  sincosf(ang, &sn, &cs);
  float t1 = src[i], t2 = src[32 + i];
  float v = (lane < 32) ? (t1 * cs - t2 * sn) : (t2 * cs + t1 * sn);
  unsigned short bv = f2bf(v);
  int d = 128 + lane;
  long inner = (long)(d >> 5) * 512 + (s & 15) * 32 + ((d & 31) ^ ((s & 3) << 3));
#pragma unroll
  for (int h = 0; h < HH; ++h) {
    long blk = ((long)(b * HH + h) * 128 + (s >> 4)) * 6;
    kf3[blk * 512 + inner] = bv;
  }
}

// ---------------- kvu (NROWS,4096) f32 -> kf3 nope (swizzled) + vt3 ----------------
__global__ __launch_bounds__(256) void k_extract_kv(const float* __restrict__ kvu,
                                                    unsigned short* __restrict__ kf3,
                                                    unsigned short* __restrict__ vt3) {
  __shared__ unsigned short vtile[64][132];
  int blk = blockIdx.x;
  int st = blk & 31;
  int h = (blk >> 5) & 15;
  int b = blk >> 9;
  int s0 = st * 64;
  long bh = (long)b * HH + h;
#pragma unroll
  for (int it = 0; it < 16; ++it) {
    int v4 = it * 256 + threadIdx.x;
    int sl = v4 >> 6;
    int c = (v4 & 63) * 4;
    int s = s0 + sl;
    float4 val = *(const float4*)&kvu[(((long)(b * SS + s)) * HH + h) * 256 + c];
    ushort4 ov = { f2bf(val.x), f2bf(val.y), f2bf(val.z), f2bf(val.w) };
    if (c < 128) {
      long addr = ((bh * 128 + (s >> 4)) * 6 + (c >> 5)) * 512 +
                  (s & 15) * 32 + ((c & 31) ^ ((s & 3) << 3));
      *(ushort4*)&kf3[addr] = ov;
    } else {
      *(ushort4*)&vtile[sl][c - 128] = ov;
    }
  }
  __syncthreads();
#pragma unroll
  for (int it = 0; it < 32; ++it) {
    int e = it * 256 + threadIdx.x;
    int d = e >> 6, sl = e & 63;
    vt3[(bh * 64 + st * 2 + (sl >> 5)) * 4096 + d * 32 + (sl & 31)] = vtile[sl][d];
  }
}

// ---------------- flash attention: LDS K-staging (m97-style), tiled-global V ----------------
// One block = one (bh, 64-row q-tile); 4 waves own 16 q-rows each. Per iter:
// stage K tile t+1 is issued right after the post-QK^T barrier (latency hides
// under softmax+PV); loop-top vmcnt(0)+barrier is then nearly free. K read from
// LDS (swizzled, all 4 waves share one 24KB staging -> 4x less L2 traffic);
// V read as batched contiguous 1KB wave-loads from the tiled global buffer.
// LDS 33KB + VGPR<=128 -> 4 blocks/CU (16 waves): TLP hides remaining latency.
__global__ __launch_bounds__(256, 4) void k_attn(const unsigned short* __restrict__ qf,
                                                 const unsigned short* __restrict__ kf3,
                                                 const unsigned short* __restrict__ vt3,
                                                 unsigned short* __restrict__ o) {
  __shared__ unsigned short kbuf[64 * 192];     // 24KB, single buffer, swizzled content
  __shared__ unsigned short pbuf[4][16 * 72];   // per-wave P transpose buffer
  int tid = threadIdx.x;
  int wave = tid >> 6, lane = tid & 63;
  int l15 = lane & 15, lhi = lane >> 4;
  int idx = blockIdx.x;
  int bh = (idx & 7) * 4 + ((idx >> 3) & 3);    // same bh -> same idx%8 (XCD slot)
  int qt = 31 - (idx >> 5);                     // heavy tiles dispatched first
  int b = bh >> 4, h = bh & 15;
  int q0 = qt * 64;
  int nt = qt + 1;
  const char* kbase = (const char*)(kf3 + (long)bh * 128 * 3072);
  const unsigned short* vfrag0 = vt3 + (long)bh * 64 * 4096 + l15 * 32 + lhi * 8;
  int swz = (l15 & 3) << 3;
  const unsigned short* kread = kbuf + l15 * 32;

  // prologue: stage K tile 0
  {
    const char* src = kbase + tid * 16;
    char* dst = (char*)kbuf + tid * 16;
#pragma unroll
    for (int p = 0; p < 6; ++p) gload16(src + p * 4096, dst + p * 4096);
  }

  // Q fragments (B-operand) — loads overlap stage(0) latency
  const unsigned short* Qb = qf + ((long)bh * SS + q0 + wave * 16 + l15) * 192 + lhi * 8;
  bf16x8 qfr[6];
#pragma unroll
  for (int ks = 0; ks < 6; ++ks) qfr[ks] = *(const bf16x8*)(Qb + ks * 32);

  float m = -3e38f, ls = 0.f;
  f32x4 acc[8] = {};
  int qin = wave * 16 + l15;

  for (int t = 0; t < nt; ++t) {
    asm volatile("s_waitcnt vmcnt(0)" ::: "memory");  // stage(t) landed (mostly pre-hidden)
    __builtin_amdgcn_s_barrier();
    __builtin_amdgcn_sched_barrier(0);

    // QK^T (swapped): sc[nf] rows k=nf*16+lhi*4+j, col q=l15; K from swizzled LDS
    f32x4 sc[4] = {};
    __builtin_amdgcn_s_setprio(1);
#pragma unroll
    for (int ks = 0; ks < 6; ++ks) {
      bf16x8 kfr[4];
#pragma unroll
      for (int nf = 0; nf < 4; ++nf)
        kfr[nf] = *(const bf16x8*)&kread[(nf * 6 + ks) * 512 + ((lhi * 8) ^ swz)];
#pragma unroll
      for (int nf = 0; nf < 4; ++nf)
        sc[nf] = mfma16(kfr[nf], qfr[ks], sc[nf]);
    }
    __builtin_amdgcn_s_setprio(0);
    __builtin_amdgcn_sched_barrier(0);
    __builtin_amdgcn_s_barrier();          // all waves done reading kbuf
    __builtin_amdgcn_sched_barrier(0);

    // V batch 0 issue (consumed after softmax ~300cy later)
    const unsigned short* vtb = vfrag0 + (long)t * 8192;
    bf16x8 v0[8];
#pragma unroll
    for (int nf = 0; nf < 8; ++nf) v0[nf] = *(const bf16x8*)(vtb + nf * 512);
    __builtin_amdgcn_sched_barrier(0);

    // stage K tile t+1 into kbuf (safe: WAR barrier above; hides under softmax+PV)
    if (t + 1 < nt) {
      const char* src = kbase + (long)(t + 1) * 24576 + tid * 16;
      char* dst = (char*)kbuf + tid * 16;
#pragma unroll
      for (int p = 0; p < 6; ++p) gload16(src + p * 4096, dst + p * 4096);
    }

    // online softmax, lane-local over k
    bool diag = (t == nt - 1);
    float mnf[4];
#pragma unroll
    for (int nf = 0; nf < 4; ++nf) {
      if (diag) {
#pragma unroll
        for (int j = 0; j < 4; ++j) {
          int kin = nf * 16 + lhi * 4 + j;
          if (kin > qin) sc[nf][j] = -3e38f;
        }
      }
      mnf[nf] = fmaxf(fmaxf(sc[nf][0], sc[nf][1]), fmaxf(sc[nf][2], sc[nf][3]));
    }
    float mx = fmaxf(fmaxf(mnf[0], mnf[1]), fmaxf(mnf[2], mnf[3]));
    mx = fmaxf(mx, __shfl_xor(mx, 16));
    mx = fmaxf(mx, __shfl_xor(mx, 32));
    if (!__all(mx <= m + 8.f)) {      // defer-rescale (exp2 domain, THR=8)
      float mn = fmaxf(m, mx);
      float alpha = exp2f(m - mn);
      m = mn;
      ls *= alpha;
#pragma unroll
      for (int nf = 0; nf < 8; ++nf)
#pragma unroll
        for (int j = 0; j < 4; ++j) acc[nf][j] *= alpha;
    }
    float pnf[4];
#pragma unroll
    for (int nf = 0; nf < 4; ++nf) {
      ushort4 pk;
      float e0 = exp2f(sc[nf][0] - m), e1 = exp2f(sc[nf][1] - m);
      float e2 = exp2f(sc[nf][2] - m), e3 = exp2f(sc[nf][3] - m);
      pnf[nf] = (e0 + e1) + (e2 + e3);
      pk.x = f2bf(e0); pk.y = f2bf(e1); pk.z = f2bf(e2); pk.w = f2bf(e3);
      *(ushort4*)&pbuf[wave][l15 * 72 + nf * 16 + lhi * 4] = pk;
    }
    float ps = (pnf[0] + pnf[1]) + (pnf[2] + pnf[3]);
    ps += __shfl_xor(ps, 16);
    ps += __shfl_xor(ps, 32);
    ls += ps;

    // PV kk=0 with v0
    {
      bf16x8 pf = *(const bf16x8*)&pbuf[wave][l15 * 72 + lhi * 8];
      __builtin_amdgcn_s_setprio(1);
#pragma unroll
      for (int nf = 0; nf < 8; ++nf) acc[nf] = mfma16(v0[nf], pf, acc[nf]);
      __builtin_amdgcn_s_setprio(0);
    }
    // V batch 1 (regs can reuse v0's), then PV kk=1
    bf16x8 v1[8];
#pragma unroll
    for (int nf = 0; nf < 8; ++nf) v1[nf] = *(const bf16x8*)(vtb + 4096 + nf * 512);
    {
      bf16x8 pf = *(const bf16x8*)&pbuf[wave][l15 * 72 + 32 + lhi * 8];
      __builtin_amdgcn_s_setprio(1);
#pragma unroll
      for (int nf = 0; nf < 8; ++nf) acc[nf] = mfma16(v1[nf], pf, acc[nf]);
      __builtin_amdgcn_s_setprio(0);
    }
  }

  // epilogue: O^T frags, row q=l15, d = nf*16+lhi*4+j -> 8B stores
  float invl = 1.f / ls;
  long orow = (long)b * SS + q0 + wave * 16 + l15;
#pragma unroll
  for (int nf = 0; nf < 8; ++nf) {
    ushort4 ov = { f2bf(acc[nf][0] * invl), f2bf(acc[nf][1] * invl),
                   f2bf(acc[nf][2] * invl), f2bf(acc[nf][3] * invl) };
    *(ushort4*)&o[orow * 2048 + h * 128 + nf * 16 + lhi * 4] = ov;
  }
}

extern "C" void kernel_launch(void* const* d_in, const int* in_sizes, int n_in,
                              void* d_out, int out_size, void* d_ws, size_t ws_size,
                              hipStream_t stream) {
  const float* x    = (const float*)d_in[0];
  const float* wqd  = (const float*)d_in[1];
  const float* bqd  = (const float*)d_in[2];
  const float* qnw  = (const float*)d_in[3];
  const float* wqu  = (const float*)d_in[4];
  const float* bqu  = (const float*)d_in[5];
  const float* wkvd = (const float*)d_in[6];
  const float* bkvd = (const float*)d_in[7];
  const float* kvnw = (const float*)d_in[8];
  const float* wkvu = (const float*)d_in[9];
  const float* bkvu = (const float*)d_in[10];
  const float* wout = (const float*)d_in[11];
  const float* bout = (const float*)d_in[12];
  float* out = (float*)d_out;

  char* ws = (char*)d_ws;
  size_t off = 0;
  auto alloc = [&](size_t sz) {
    char* p = ws + off;
    off += (sz + 255) & ~(size_t)255;
    return p;
  };
  unsigned short* xb    = (unsigned short*)alloc((size_t)NROWS * 2048 * 2);
  unsigned short* wqdt  = (unsigned short*)alloc((size_t)1536 * 2048 * 2);
  unsigned short* wqut  = (unsigned short*)alloc((size_t)3072 * 1536 * 2);
  unsigned short* wkvdt = (unsigned short*)alloc((size_t)640 * 2048 * 2);
  unsigned short* wkvut = (unsigned short*)alloc((size_t)4096 * 512 * 2);
  unsigned short* woutt = (unsigned short*)alloc((size_t)2048 * 2048 * 2);
  unsigned short* qn    = (unsigned short*)alloc((size_t)NROWS * 1536 * 2);
  unsigned short* kvn   = (unsigned short*)alloc((size_t)NROWS * 512 * 2);
  unsigned short* qfb   = (unsigned short*)alloc((size_t)32 * SS * 192 * 2);
  unsigned short* kfb   = (unsigned short*)alloc((size_t)32 * SS * 192 * 2);   // kf3 tiled+swz
  unsigned short* vtb   = (unsigned short*)alloc((size_t)32 * 128 * SS * 2);   // vt3 tiled
  unsigned short* ob    = (unsigned short*)alloc((size_t)NROWS * 2048 * 2);
  float* sA = (float*)alloc((size_t)NROWS * 1536 * 4);   // qd, then kvd
  float* sB = (float*)alloc((size_t)NROWS * 4096 * 4);   // q,  then kvu

  // conversions
  k_convert<<<2048, 256, 0, stream>>>(x, xb, (long)NROWS * 2048 / 4);
  k_transpose<<<dim3(48, 64), 256, 0, stream>>>(wqd, wqdt, 2048, 1536, 1536);
  k_transpose<<<dim3(96, 48), 256, 0, stream>>>(wqu, wqut, 1536, 3072, 3072);
  k_transpose<<<dim3(20, 64), 256, 0, stream>>>(wkvd, wkvdt, 2048, 576, 640);
  k_transpose<<<dim3(128, 16), 256, 0, stream>>>(wkvu, wkvut, 512, 4096, 4096);
  k_transpose<<<dim3(64, 64), 256, 0, stream>>>(wout, woutt, 2048, 2048, 2048);

  // q path
  k_gemm<<<32 * 12, 256, 0, stream>>>(xb, wqdt, bqd, sA, NROWS, 1536, 2048);
  k_rmsnorm<<<NROWS, 256, 0, stream>>>(sA, qnw, qn, 1536, 1536);
  k_gemm<<<32 * 24, 256, 0, stream>>>(qn, wqut, bqu, sB, NROWS, 3072, 1536);
  k_extract_q<<<NROWS * HH / 4, 256, 0, stream>>>(sB, qfb);

  // kv path
  k_gemm<<<32 * 5, 256, 0, stream>>>(xb, wkvdt, bkvd, sA, NROWS, 576, 2048);
  k_rmsnorm<<<NROWS, 256, 0, stream>>>(sA, kvnw, kvn, 512, 576);
  k_extract_krope<<<NROWS, 64, 0, stream>>>(sA, kfb);
  k_gemm<<<32 * 32, 256, 0, stream>>>(kvn, wkvut, bkvu, sB, NROWS, 4096, 512);
  k_extract_kv<<<1024, 256, 0, stream>>>(sB, kfb, vtb);

  // attention: 1024 blocks (32 bh x 32 q-tiles), LDS K-staging + tiled V
  k_attn<<<1024, 256, 0, stream>>>(qfb, kfb, vtb, ob);

  // output projection
  k_gemm<<<32 * 16, 256, 0, stream>>>(ob, woutt, bout, out, NROWS, 2048, 2048);
}

// Round 9
// 446.652 us; speedup vs baseline: 1.5959x; 1.0580x over previous
//
#include <hip/hip_runtime.h>
#include <hip/hip_bf16.h>
#include <math.h>

#define HH 16
#define SS 2048
#define BBATCH 2
#define NROWS 4096   // B*S

typedef __attribute__((ext_vector_type(8))) __bf16 bf16x8;
typedef __attribute__((ext_vector_type(4))) float f32x4;
typedef const __attribute__((address_space(1))) unsigned int* gas1_t;
typedef __attribute__((address_space(3))) unsigned int* las3_t;

__device__ __forceinline__ unsigned short f2bf(float f) {
  unsigned u = __builtin_bit_cast(unsigned, f);
  u += 0x7fffu + ((u >> 16) & 1u);
  return (unsigned short)(u >> 16);
}
__device__ __forceinline__ unsigned cvtpk_bf16(float a, float b) {
  unsigned r;
  asm("v_cvt_pk_bf16_f32 %0, %1, %2" : "=v"(r) : "v"(a), "v"(b));
  return r;
}

__device__ __forceinline__ void gload16(const void* g, void* l) {
  __builtin_amdgcn_global_load_lds((gas1_t)g, (las3_t)l, 16, 0, 0);
}
__device__ __forceinline__ f32x4 mfma16(bf16x8 a, bf16x8 b, f32x4 c) {
  return __builtin_amdgcn_mfma_f32_16x16x32_bf16(a, b, c, 0, 0, 0);
}

// ---------------- f32 -> bf16 copy (same layout) ----------------
__global__ __launch_bounds__(256) void k_convert(const float* __restrict__ in,
                                                 unsigned short* __restrict__ out, long n4) {
  long i = (long)blockIdx.x * blockDim.x + threadIdx.x;
  long stride = (long)gridDim.x * blockDim.x;
  for (; i < n4; i += stride) {
    float4 v = ((const float4*)in)[i];
    ushort4 o = { f2bf(v.x), f2bf(v.y), f2bf(v.z), f2bf(v.w) };
    ((ushort4*)out)[i] = o;
  }
}

// ---------------- W (K,N) f32 -> Wt (Npad,K) bf16 ----------------
__global__ __launch_bounds__(256) void k_transpose(const float* __restrict__ W,
                                                   unsigned short* __restrict__ Wt,
                                                   int K, int N, int Npad) {
  __shared__ float tile[32][33];
  int n0 = blockIdx.x * 32, k0 = blockIdx.y * 32;
  int tx = threadIdx.x & 31, ty = threadIdx.x >> 5;
  for (int i = ty; i < 32; i += 8) {
    int k = k0 + i, n = n0 + tx;
    tile[i][tx] = (k < K && n < N) ? W[(long)k * N + n] : 0.f;
  }
  __syncthreads();
  for (int i = ty; i < 32; i += 8) {
    int n = n0 + i, k = k0 + tx;
    if (n < Npad && k < K) Wt[(long)n * K + k] = f2bf(tile[tx][i]);
  }
}

// ---------------- merged bias for qd+kvd GEMM ----------------
__global__ __launch_bounds__(256) void k_bias_merge(const float* __restrict__ bqd,
                                                    const float* __restrict__ bkvd,
                                                    float* __restrict__ mb) {
  int i = blockIdx.x * 256 + threadIdx.x;
  if (i < 2176) mb[i] = i < 1536 ? bqd[i] : (i < 2112 ? bkvd[i - 1536] : 0.f);
}

// ---------------- rope cos/sin table: tab[s*32+i] = {cos, sin} ----------------
__global__ __launch_bounds__(64) void k_rope_table(float2* __restrict__ tab) {
  int s = blockIdx.x * 2 + (threadIdx.x >> 5);
  int i = threadIdx.x & 31;
  float inv = powf(10000.f, -(float)i / 32.f);
  float ang = (float)s * inv;
  float sn, cs;
  sincosf(ang, &sn, &cs);
  tab[s * 32 + i] = make_float2(cs, sn);
}

// ---------------- GEMM: C(M,N) f32 = A(M,K)bf16 * Bt(Npad,K)bf16 + bias ----------------
__global__ __launch_bounds__(256) void k_gemm(const unsigned short* __restrict__ A,
                                              const unsigned short* __restrict__ Bt,
                                              const float* __restrict__ bias,
                                              float* __restrict__ C,
                                              int M, int N, int K) {
  __shared__ unsigned short lA[128 * 32];
  __shared__ unsigned short lB[128 * 32];
  int tid = threadIdx.x;
  int wave = tid >> 6, lane = tid & 63;
  int l15 = lane & 15, lhi = lane >> 4;
  int ntn = (N + 127) >> 7;
  int tm = blockIdx.x / ntn, tn = blockIdx.x % ntn;
  long row0 = (long)tm * 128, col0 = (long)tn * 128;
  int wr = wave >> 1, wc = wave & 1;

  const unsigned short* gA = A + (row0 + (tid >> 2)) * K + (tid & 3) * 8;
  const unsigned short* gB = Bt + (col0 + (tid >> 2)) * K + (tid & 3) * 8;
  unsigned short* lA0 = &lA[tid * 8];
  unsigned short* lB0 = &lB[tid * 8];

  f32x4 acc[4][4] = {};
  for (int k0 = 0; k0 < K; k0 += 32) {
    __syncthreads();
    gload16(gA + k0, lA0);
    gload16(gA + (long)64 * K + k0, lA0 + 2048);
    gload16(gB + k0, lB0);
    gload16(gB + (long)64 * K + k0, lB0 + 2048);
    asm volatile("s_waitcnt vmcnt(0)" ::: "memory");
    __syncthreads();
    bf16x8 af[4], bfr[4];
#pragma unroll
    for (int i = 0; i < 4; ++i) {
      af[i]  = *(const bf16x8*)&lA[(wr * 64 + i * 16 + l15) * 32 + lhi * 8];
      bfr[i] = *(const bf16x8*)&lB[(wc * 64 + i * 16 + l15) * 32 + lhi * 8];
    }
#pragma unroll
    for (int i = 0; i < 4; ++i)
#pragma unroll
      for (int j = 0; j < 4; ++j)
        acc[i][j] = mfma16(af[i], bfr[j], acc[i][j]);
  }
#pragma unroll
  for (int i = 0; i < 4; ++i)
#pragma unroll
    for (int j = 0; j < 4; ++j) {
      long r = row0 + wr * 64 + i * 16 + lhi * 4;
      long c = col0 + wc * 64 + j * 16 + l15;
      if (c < N) {
        float bv = bias[c];
#pragma unroll
        for (int rr = 0; rr < 4; ++rr)
          C[(r + rr) * N + c] = acc[i][j][rr] + bv;
      }
    }
}

// ---------------- GEMM + fused q extract: qn(M,K) x wqut -> qf bf16 (rope+scale) ----------------
// N=3072 = 16 heads x 192. Per wave the 64-col range has base%192 in {0,64,128};
// rope applies only when 128: pairs (d, d+32) are acc frags j and j+2 of the SAME lane.
__global__ __launch_bounds__(256) void k_gemm_qf(const unsigned short* __restrict__ A,
                                                 const unsigned short* __restrict__ Bt,
                                                 const float* __restrict__ bias,
                                                 const float2* __restrict__ rtab,
                                                 unsigned short* __restrict__ qf,
                                                 int M, int N, int K) {
  __shared__ unsigned short lA[128 * 32];
  __shared__ unsigned short lB[128 * 32];
  int tid = threadIdx.x;
  int wave = tid >> 6, lane = tid & 63;
  int l15 = lane & 15, lhi = lane >> 4;
  int ntn = (N + 127) >> 7;
  int tm = blockIdx.x / ntn, tn = blockIdx.x % ntn;
  long row0 = (long)tm * 128, col0 = (long)tn * 128;
  int wr = wave >> 1, wc = wave & 1;

  const unsigned short* gA = A + (row0 + (tid >> 2)) * K + (tid & 3) * 8;
  const unsigned short* gB = Bt + (col0 + (tid >> 2)) * K + (tid & 3) * 8;
  unsigned short* lA0 = &lA[tid * 8];
  unsigned short* lB0 = &lB[tid * 8];

  f32x4 acc[4][4] = {};
  for (int k0 = 0; k0 < K; k0 += 32) {
    __syncthreads();
    gload16(gA + k0, lA0);
    gload16(gA + (long)64 * K + k0, lA0 + 2048);
    gload16(gB + k0, lB0);
    gload16(gB + (long)64 * K + k0, lB0 + 2048);
    asm volatile("s_waitcnt vmcnt(0)" ::: "memory");
    __syncthreads();
    bf16x8 af[4], bfr[4];
#pragma unroll
    for (int i = 0; i < 4; ++i) {
      af[i]  = *(const bf16x8*)&lA[(wr * 64 + i * 16 + l15) * 32 + lhi * 8];
      bfr[i] = *(const bf16x8*)&lB[(wc * 64 + i * 16 + l15) * 32 + lhi * 8];
    }
#pragma unroll
    for (int i = 0; i < 4; ++i)
#pragma unroll
      for (int j = 0; j < 4; ++j)
        acc[i][j] = mfma16(af[i], bfr[j], acc[i][j]);
  }

  const float scq = 0.07216878364870322f * 1.4426950408889634f;  // 192^-0.5 * log2(e)
  int base = (int)col0 + wc * 64;
  int h = base / 192;
  int m192 = base - h * 192;   // 0, 64, or 128 (wave-uniform)
  float bv[4];
#pragma unroll
  for (int j = 0; j < 4; ++j) bv[j] = bias[base + j * 16 + l15];

#pragma unroll
  for (int i = 0; i < 4; ++i) {
#pragma unroll
    for (int rr = 0; rr < 4; ++rr) {
      long r = row0 + wr * 64 + i * 16 + lhi * 4 + rr;
      int s = (int)(r & 2047), b = (int)(r >> 11);
      unsigned short* dst = qf + (((long)(b * HH + h)) * SS + s) * 192;
      if (m192 < 128) {
#pragma unroll
        for (int j = 0; j < 4; ++j)
          dst[m192 + j * 16 + l15] = f2bf((acc[i][j][rr] + bv[j]) * scq);
      } else {
#pragma unroll
        for (int j = 0; j < 2; ++j) {
          int ifq = j * 16 + l15;
          float2 cs = rtab[s * 32 + ifq];
          float v1 = acc[i][j][rr] + bv[j];
          float v2 = acc[i][j + 2][rr] + bv[j + 2];
          dst[128 + ifq] = f2bf((v1 * cs.x - v2 * cs.y) * scq);
          dst[160 + ifq] = f2bf((v2 * cs.x + v1 * cs.y) * scq);
        }
      }
    }
  }
}

// ---------------- RMSNorm: f32 (rows, ldx) -> bf16 (rows, L) ----------------
__global__ __launch_bounds__(256) void k_rmsnorm(const float* __restrict__ X,
                                                 const float* __restrict__ w,
                                                 unsigned short* __restrict__ Y,
                                                 int L, int ldx) {
  long row = blockIdx.x;
  const float* x = X + row * ldx;
  float ss = 0.f;
  int n4 = L >> 2;
  for (int i = threadIdx.x; i < n4; i += 256) {
    float4 v = ((const float4*)x)[i];
    ss += v.x * v.x + v.y * v.y + v.z * v.z + v.w * v.w;
  }
  for (int off = 32; off > 0; off >>= 1) ss += __shfl_xor(ss, off);
  __shared__ float sb[4];
  if ((threadIdx.x & 63) == 0) sb[threadIdx.x >> 6] = ss;
  __syncthreads();
  float scale = rsqrtf((sb[0] + sb[1] + sb[2] + sb[3]) / (float)L + 1e-6f);
  unsigned short* y = Y + row * L;
  for (int i = threadIdx.x; i < L; i += 256)
    y[i] = f2bf(x[i] * scale * w[i]);
}

// K fragment-tiled, chunk-major (conflict-free LDS): per (bh, s16=s>>4, ks=d>>5) a 1KB
// tile stored [4 dchunk][16 s][8 d]:
//   addr(bh,s,d) = ((bh*128 + (s>>4))*6 + (d>>5))*512 + ((d>>3)&3)*128 + (s&15)*8 + (d&7)
// V fragment-tiled: vt3[bh][s>>5][d(128)][s&31]

// ---------------- kvd rope cols (sC layout, stride 2176, offset 2048) -> kf3 ----------------
__global__ __launch_bounds__(64) void k_extract_krope(const float* __restrict__ sC,
                                                      unsigned short* __restrict__ kf3) {
  int bs = blockIdx.x;
  int lane = threadIdx.x;
  int s = bs & (SS - 1), b = bs >> 11;
  const float* src = sC + (long)bs * 2176 + 2048;
  int i = lane & 31;
  float inv = powf(10000.f, -(float)i / 32.f);
  float ang = (float)s * inv;
  float sn, cs;
  sincosf(ang, &sn, &cs);
  float t1 = src[i], t2 = src[32 + i];
  float v = (lane < 32) ? (t1 * cs - t2 * sn) : (t2 * cs + t1 * sn);
  unsigned short bv = f2bf(v);
  int d = 128 + lane;
  long inner = (long)(d >> 5) * 512 + ((d >> 3) & 3) * 128 + (s & 15) * 8 + (d & 7);
#pragma unroll
  for (int h = 0; h < HH; ++h) {
    long blk = ((long)(b * HH + h) * 128 + (s >> 4)) * 6;
    kf3[blk * 512 + inner] = bv;
  }
}

// ---------------- kvu (NROWS,4096) f32 -> kf3 nope + vt3 ----------------
__global__ __launch_bounds__(256) void k_extract_kv(const float* __restrict__ kvu,
                                                    unsigned short* __restrict__ kf3,
                                                    unsigned short* __restrict__ vt3) {
  __shared__ unsigned short vtile[64][132];
  int blk = blockIdx.x;
  int st = blk & 31;
  int h = (blk >> 5) & 15;
  int b = blk >> 9;
  int s0 = st * 64;
  long bh = (long)b * HH + h;
#pragma unroll
  for (int it = 0; it < 16; ++it) {
    int v4 = it * 256 + threadIdx.x;
    int sl = v4 >> 6;
    int c = (v4 & 63) * 4;
    int s = s0 + sl;
    float4 val = *(const float4*)&kvu[(((long)(b * SS + s)) * HH + h) * 256 + c];
    ushort4 ov = { f2bf(val.x), f2bf(val.y), f2bf(val.z), f2bf(val.w) };
    if (c < 128) {
      long addr = ((bh * 128 + (s >> 4)) * 6 + (c >> 5)) * 512 +
                  ((c >> 3) & 3) * 128 + (s & 15) * 8 + (c & 7);
      *(ushort4*)&kf3[addr] = ov;
    } else {
      *(ushort4*)&vtile[sl][c - 128] = ov;
    }
  }
  __syncthreads();
#pragma unroll
  for (int it = 0; it < 32; ++it) {
    int e = it * 256 + threadIdx.x;
    int d = e >> 6, sl = e & 63;
    vt3[(bh * 64 + st * 2 + (sl >> 5)) * 4096 + d * 32 + (sl & 31)] = vtile[sl][d];
  }
}

// ---------------- flash attention: LDS K-staging, conflict-free tiles, tiled-global V ----------------
// Block mapping: g=idx>>8, j=idx&255, a=j>>5, bh=j&31; qt in {a, a+8, 23-a, 31-a} per g.
// Blocks j, j+256, j+512, j+768 land on the same CU (4/CU resident): constant work
// sum (66 iters) per CU and SAME bh per CU (K/V L2 reuse x4, bh partitioned by XCD).
// K LDS tiles are chunk-major so the fragment read addr = base + lane*16 (linear,
// conflict-free). P->bf16 via v_cvt_pk. V = contiguous 1KB wave-loads from global.
__global__ __launch_bounds__(256, 4) void k_attn(const unsigned short* __restrict__ qf,
                                                 const unsigned short* __restrict__ kf3,
                                                 const unsigned short* __restrict__ vt3,
                                                 unsigned short* __restrict__ o) {
  __shared__ unsigned short kbuf[64 * 192];     // 24KB, single buffer
  __shared__ unsigned short pbuf[4][16 * 72];   // per-wave P transpose buffer
  int tid = threadIdx.x;
  int wave = tid >> 6, lane = tid & 63;
  int l15 = lane & 15, lhi = lane >> 4;
  int idx = blockIdx.x;
  int g = idx >> 8, j = idx & 255;
  int a = j >> 5, bh = j & 31;
  int qt = g < 2 ? (g == 0 ? a : a + 8) : (g == 2 ? 23 - a : 31 - a);
  int b = bh >> 4, h = bh & 15;
  int q0 = qt * 64;
  int nt = qt + 1;
  const char* kbase = (const char*)(kf3 + (long)bh * 128 * 3072);
  const unsigned short* vfrag0 = vt3 + (long)bh * 64 * 4096 + l15 * 32 + lhi * 8;
  const unsigned short* kread = kbuf + lane * 8;

  // prologue: stage K tile 0
  {
    const char* src = kbase + tid * 16;
    char* dst = (char*)kbuf + tid * 16;
#pragma unroll
    for (int p = 0; p < 6; ++p) gload16(src + p * 4096, dst + p * 4096);
  }

  // Q fragments (B-operand) — loads overlap stage(0) latency
  const unsigned short* Qb = qf + ((long)bh * SS + q0 + wave * 16 + l15) * 192 + lhi * 8;
  bf16x8 qfr[6];
#pragma unroll
  for (int ks = 0; ks < 6; ++ks) qfr[ks] = *(const bf16x8*)(Qb + ks * 32);

  float m = -3e38f, ls = 0.f;
  f32x4 acc[8] = {};
  int qin = wave * 16 + l15;

  for (int t = 0; t < nt; ++t) {
    asm volatile("s_waitcnt vmcnt(0)" ::: "memory");  // stage(t) landed (mostly pre-hidden)
    __builtin_amdgcn_s_barrier();
    __builtin_amdgcn_sched_barrier(0);

    // QK^T (swapped): sc[nf] rows k=nf*16+lhi*4+j, col q=l15; conflict-free LDS reads
    f32x4 sc[4] = {};
    __builtin_amdgcn_s_setprio(1);
#pragma unroll
    for (int ks = 0; ks < 6; ++ks) {
      bf16x8 kfr[4];
#pragma unroll
      for (int nf = 0; nf < 4; ++nf)
        kfr[nf] = *(const bf16x8*)&kread[(nf * 6 + ks) * 512];
#pragma unroll
      for (int nf = 0; nf < 4; ++nf)
        sc[nf] = mfma16(kfr[nf], qfr[ks], sc[nf]);
    }
    __builtin_amdgcn_s_setprio(0);
    __builtin_amdgcn_sched_barrier(0);
    __builtin_amdgcn_s_barrier();          // all waves done reading kbuf
    __builtin_amdgcn_sched_barrier(0);

    // V batch 0 issue (consumed after softmax ~300cy later)
    const unsigned short* vtb = vfrag0 + (long)t * 8192;
    bf16x8 v0[8];
#pragma unroll
    for (int nf = 0; nf < 8; ++nf) v0[nf] = *(const bf16x8*)(vtb + nf * 512);
    __builtin_amdgcn_sched_barrier(0);

    // stage K tile t+1 into kbuf (safe: WAR barrier above; hides under softmax+PV)
    if (t + 1 < nt) {
      const char* src = kbase + (long)(t + 1) * 24576 + tid * 16;
      char* dst = (char*)kbuf + tid * 16;
#pragma unroll
      for (int p = 0; p < 6; ++p) gload16(src + p * 4096, dst + p * 4096);
    }

    // online softmax, lane-local over k
    bool diag = (t == nt - 1);
    float mnf[4];
#pragma unroll
    for (int nf = 0; nf < 4; ++nf) {
      if (diag) {
#pragma unroll
        for (int jj = 0; jj < 4; ++jj) {
          int kin = nf * 16 + lhi * 4 + jj;
          if (kin > qin) sc[nf][jj] = -3e38f;
        }
      }
      mnf[nf] = fmaxf(fmaxf(sc[nf][0], sc[nf][1]), fmaxf(sc[nf][2], sc[nf][3]));
    }
    float mx = fmaxf(fmaxf(mnf[0], mnf[1]), fmaxf(mnf[2], mnf[3]));
    mx = fmaxf(mx, __shfl_xor(mx, 16));
    mx = fmaxf(mx, __shfl_xor(mx, 32));
    if (!__all(mx <= m + 8.f)) {      // defer-rescale (exp2 domain, THR=8)
      float mn = fmaxf(m, mx);
      float alpha = exp2f(m - mn);
      m = mn;
      ls *= alpha;
#pragma unroll
      for (int nf = 0; nf < 8; ++nf)
#pragma unroll
        for (int jj = 0; jj < 4; ++jj) acc[nf][jj] *= alpha;
    }
    float pnf[4];
#pragma unroll
    for (int nf = 0; nf < 4; ++nf) {
      float e0 = exp2f(sc[nf][0] - m), e1 = exp2f(sc[nf][1] - m);
      float e2 = exp2f(sc[nf][2] - m), e3 = exp2f(sc[nf][3] - m);
      pnf[nf] = (e0 + e1) + (e2 + e3);
      uint2 pk = { cvtpk_bf16(e0, e1), cvtpk_bf16(e2, e3) };
      *(uint2*)&pbuf[wave][l15 * 72 + nf * 16 + lhi * 4] = pk;
    }
    float ps = (pnf[0] + pnf[1]) + (pnf[2] + pnf[3]);
    ps += __shfl_xor(ps, 16);
    ps += __shfl_xor(ps, 32);
    ls += ps;

    // PV kk=0 with v0
    {
      bf16x8 pf = *(const bf16x8*)&pbuf[wave][l15 * 72 + lhi * 8];
      __builtin_amdgcn_s_setprio(1);
#pragma unroll
      for (int nf = 0; nf < 8; ++nf) acc[nf] = mfma16(v0[nf], pf, acc[nf]);
      __builtin_amdgcn_s_setprio(0);
    }
    // V batch 1, then PV kk=1
    bf16x8 v1[8];
#pragma unroll
    for (int nf = 0; nf < 8; ++nf) v1[nf] = *(const bf16x8*)(vtb + 4096 + nf * 512);
    {
      bf16x8 pf = *(const bf16x8*)&pbuf[wave][l15 * 72 + 32 + lhi * 8];
      __builtin_amdgcn_s_setprio(1);
#pragma unroll
      for (int nf = 0; nf < 8; ++nf) acc[nf] = mfma16(v1[nf], pf, acc[nf]);
      __builtin_amdgcn_s_setprio(0);
    }
  }

  // epilogue: O^T frags, row q=l15, d = nf*16+lhi*4+j -> 8B stores
  float invl = 1.f / ls;
  long orow = (long)b * SS + q0 + wave * 16 + l15;
#pragma unroll
  for (int nf = 0; nf < 8; ++nf) {
    ushort4 ov = { f2bf(acc[nf][0] * invl), f2bf(acc[nf][1] * invl),
                   f2bf(acc[nf][2] * invl), f2bf(acc[nf][3] * invl) };
    *(ushort4*)&o[orow * 2048 + h * 128 + nf * 16 + lhi * 4] = ov;
  }
}

extern "C" void kernel_launch(void* const* d_in, const int* in_sizes, int n_in,
                              void* d_out, int out_size, void* d_ws, size_t ws_size,
                              hipStream_t stream) {
  const float* x    = (const float*)d_in[0];
  const float* wqd  = (const float*)d_in[1];
  const float* bqd  = (const float*)d_in[2];
  const float* qnw  = (const float*)d_in[3];
  const float* wqu  = (const float*)d_in[4];
  const float* bqu  = (const float*)d_in[5];
  const float* wkvd = (const float*)d_in[6];
  const float* bkvd = (const float*)d_in[7];
  const float* kvnw = (const float*)d_in[8];
  const float* wkvu = (const float*)d_in[9];
  const float* bkvu = (const float*)d_in[10];
  const float* wout = (const float*)d_in[11];
  const float* bout = (const float*)d_in[12];
  float* out = (float*)d_out;

  char* ws = (char*)d_ws;
  size_t off = 0;
  auto alloc = [&](size_t sz) {
    char* p = ws + off;
    off += (sz + 255) & ~(size_t)255;
    return p;
  };
  unsigned short* xb    = (unsigned short*)alloc((size_t)NROWS * 2048 * 2);
  unsigned short* wqkt  = (unsigned short*)alloc((size_t)2176 * 2048 * 2);  // [wqd;wkvd]^T
  unsigned short* wqut  = (unsigned short*)alloc((size_t)3072 * 1536 * 2);
  unsigned short* wkvut = (unsigned short*)alloc((size_t)4096 * 512 * 2);
  unsigned short* woutt = (unsigned short*)alloc((size_t)2048 * 2048 * 2);
  unsigned short* qn    = (unsigned short*)alloc((size_t)NROWS * 1536 * 2);
  unsigned short* kvn   = (unsigned short*)alloc((size_t)NROWS * 512 * 2);
  unsigned short* qfb   = (unsigned short*)alloc((size_t)32 * SS * 192 * 2);
  unsigned short* kfb   = (unsigned short*)alloc((size_t)32 * SS * 192 * 2);   // kf3 tiled
  unsigned short* vtb   = (unsigned short*)alloc((size_t)32 * 128 * SS * 2);   // vt3 tiled
  unsigned short* ob    = (unsigned short*)alloc((size_t)NROWS * 2048 * 2);
  float*  mbias = (float*)alloc((size_t)2176 * 4);
  float2* rtab  = (float2*)alloc((size_t)SS * 32 * 8);
  float* sC = (float*)alloc((size_t)NROWS * 2176 * 4);   // merged qd|kvd output
  float* sB = (float*)alloc((size_t)NROWS * 4096 * 4);   // kvu output

  // conversions / tables
  k_convert<<<2048, 256, 0, stream>>>(x, xb, (long)NROWS * 2048 / 4);
  k_transpose<<<dim3(48, 64), 256, 0, stream>>>(wqd, wqkt, 2048, 1536, 1536);
  k_transpose<<<dim3(20, 64), 256, 0, stream>>>(wkvd, wqkt + (size_t)1536 * 2048, 2048, 576, 640);
  k_transpose<<<dim3(96, 48), 256, 0, stream>>>(wqu, wqut, 1536, 3072, 3072);
  k_transpose<<<dim3(128, 16), 256, 0, stream>>>(wkvu, wkvut, 512, 4096, 4096);
  k_transpose<<<dim3(64, 64), 256, 0, stream>>>(wout, woutt, 2048, 2048, 2048);
  k_bias_merge<<<9, 256, 0, stream>>>(bqd, bkvd, mbias);
  k_rope_table<<<SS / 2, 64, 0, stream>>>(rtab);

  // down-projections (merged): sC = x @ [wqd|wkvd] + bias
  k_gemm<<<32 * 17, 256, 0, stream>>>(xb, wqkt, mbias, sC, NROWS, 2176, 2048);

  // q path: rmsnorm -> up-proj fused with rope/scale/layout
  k_rmsnorm<<<NROWS, 256, 0, stream>>>(sC, qnw, qn, 1536, 2176);
  k_gemm_qf<<<32 * 24, 256, 0, stream>>>(qn, wqut, bqu, rtab, qfb, NROWS, 3072, 1536);

  // kv path
  k_rmsnorm<<<NROWS, 256, 0, stream>>>(sC + 1536, kvnw, kvn, 512, 2176);
  k_extract_krope<<<NROWS, 64, 0, stream>>>(sC, kfb);
  k_gemm<<<32 * 32, 256, 0, stream>>>(kvn, wkvut, bkvu, sB, NROWS, 4096, 512);
  k_extract_kv<<<1024, 256, 0, stream>>>(sB, kfb, vtb);

  // attention: 1024 blocks, CU-balanced qt mapping, conflict-free K tiles
  k_attn<<<1024, 256, 0, stream>>>(qfb, kfb, vtb, ob);

  // output projection
  k_gemm<<<32 * 16, 256, 0, stream>>>(ob, woutt, bout, out, NROWS, 2048, 2048);
}